// Round 13
// baseline (535.933 us; speedup 1.0000x reference)
//
#include <hip/hip_runtime.h>

// Round 27: R26 (A-dbuf, 7 barriers) + launch_bounds(256,2) + static
// 2-deep B pipeline (R25 structure).
// R26 post-mortem: barrier-halving correct but net -20us (occupancy 32->22%
// at LDS 69.6KB). The 2-block config frees VGPRs: 2 waves/SIMD -> 256
// VGPR/wave available; bounds(256,3) made the allocator refuse R25's
// 2-deep B (allocated 84 + spilled). bounds(256,2) licenses the full file:
// B0+B1 (64 VGPR) fit statically -> per-kt B refill coverage ~2 kt of MFMA
// (~460cy) >= L2 latency, closing the last identified exposed stall (R23:
// GEMM chain = 84% of kernel). R25's mfma_body was correctness-proven
// (absmax 0.0078125); only its spill was the problem. Tripwires: VGPR must
// rise >>92 and WRITE_SIZE stay ~1.5MB, dur must beat R24's 447.
// fp32 fallback (R11, proven) retained for tiny ws.

typedef __attribute__((ext_vector_type(8))) _Float16 half8;
typedef __attribute__((ext_vector_type(4))) float f32x4;

#define AS 264   // fp16 A stride (+8 pad)

#define NHALF  393216    // elements per precision plane in ws
#define OFF_WC1 0        // [2][256][256]
#define OFF_WC2 131072
#define OFF_W1  262144   // [256][256]
#define OFF_W2  327680
#define WS_NEED 1572864  // bytes = 2 planes x 393216 halves x 2B

__device__ __forceinline__ float sigm(float y) { return 1.f / (1.f + __expf(-y)); }

// ---- DPP lane-sum helper (R24 proven): v + perm(v), within 16-lane row ----
template <int CTRL>
__device__ __forceinline__ float dppadd(float v) {
  union { float f; int i; } u, r;
  u.f = v;
  r.i = __builtin_amdgcn_update_dpp(0, u.i, CTRL, 0xf, 0xf, true);
  return v + r.f;
}
#define DPP_X1 0xB1   // quad_perm [1,0,3,2]  == lane^1
#define DPP_X2 0x4E   // quad_perm [2,3,0,1]  == lane^2
#define DPP_X7 0x141  // row_half_mirror      == lane^7 (quad-sum partner)
#define DPP_XF 0x140  // row_mirror           == lane^15 (8-group partner)

__device__ __forceinline__ float gsum8(float v) {
  v = dppadd<DPP_X1>(v);
  v = dppadd<DPP_X2>(v);
  v = dppadd<DPP_X7>(v);
  return v;
}
__device__ __forceinline__ float gsum16(float v) {
  v = dppadd<DPP_X1>(v);
  v = dppadd<DPP_X2>(v);
  v = dppadd<DPP_X7>(v);
  v = dppadd<DPP_XF>(v);
  return v;
}

// ---- prep: pack weights as fp16 hi/lo planes: wsl = wsh + NHALF ----
__global__ __launch_bounds__(256) void prep(const float* __restrict__ c1w,
                                            const float* __restrict__ c2w,
                                            const float* __restrict__ w1,
                                            const float* __restrict__ w2,
                                            _Float16* __restrict__ ws) {
  int i = blockIdx.x * 256 + threadIdx.x;  // 0..131071
  {
    float v = c1w[(size_t)i * 9 + 4];
    _Float16 h = (_Float16)v;
    ws[OFF_WC1 + i] = h;
    ws[NHALF + OFF_WC1 + i] = (_Float16)(v - (float)h);
  }
  {
    float v = c2w[(size_t)i * 9 + 4];
    _Float16 h = (_Float16)v;
    ws[OFF_WC2 + i] = h;
    ws[NHALF + OFF_WC2 + i] = (_Float16)(v - (float)h);
  }
  if (i < 65536) {
    float v = w1[i];
    _Float16 h = (_Float16)v;
    ws[OFF_W1 + i] = h;
    ws[NHALF + OFF_W1 + i] = (_Float16)(v - (float)h);
    v = w2[i];
    h = (_Float16)v;
    ws[OFF_W2 + i] = h;
    ws[NHALF + OFF_W2 + i] = (_Float16)(v - (float)h);
  }
}

// ---- hi/lo split store into A planes ----
__device__ __forceinline__ void hl_store(_Float16* __restrict__ Ah,
                                         _Float16* __restrict__ Al,
                                         int idx, float v) {
  _Float16 h = (_Float16)v;
  Ah[idx] = h;
  Al[idx] = (_Float16)(v - (float)h);
}

// ---- B fragment registers: one kt batch (named structs -> static regs) ----
struct BF { half8 h[4], l[4]; };

template <int KT>
__device__ __forceinline__ void loadB(BF& B,
    const _Float16* __restrict__ Wh, const _Float16* __restrict__ Wl,
    size_t boff) {
  #pragma unroll
  for (int nt = 0; nt < 4; nt++) {
    B.h[nt] = *(const half8*)(Wh + boff + (nt << 12) + KT * 32);
    B.l[nt] = *(const half8*)(Wl + boff + (nt << 12) + KT * 32);
  }
}

// ---- one kt step: 4 A-frag LDS reads + 24 MFMA, product-major order
// (dependent writes to same acc 8 MFMAs apart; per-element accumulation
// order hi*h, hi*l, lo*h unchanged -> bit-identical). R25-proven. ----
template <int KT>
__device__ __forceinline__ void computeKt(f32x4 acc[2][4],
    const _Float16* __restrict__ Ah, const _Float16* __restrict__ Al,
    int aoff, const BF& B) {
  half8 ah0 = *(const half8*)(Ah + aoff + KT * 32);
  half8 ah1 = *(const half8*)(Ah + aoff + 16 * AS + KT * 32);
  half8 al0 = *(const half8*)(Al + aoff + KT * 32);
  half8 al1 = *(const half8*)(Al + aoff + 16 * AS + KT * 32);
  #pragma unroll
  for (int nt = 0; nt < 4; nt++)
    acc[0][nt] = __builtin_amdgcn_mfma_f32_16x16x32_f16(ah0, B.h[nt], acc[0][nt], 0, 0, 0);
  #pragma unroll
  for (int nt = 0; nt < 4; nt++)
    acc[1][nt] = __builtin_amdgcn_mfma_f32_16x16x32_f16(ah1, B.h[nt], acc[1][nt], 0, 0, 0);
  #pragma unroll
  for (int nt = 0; nt < 4; nt++)
    acc[0][nt] = __builtin_amdgcn_mfma_f32_16x16x32_f16(ah0, B.l[nt], acc[0][nt], 0, 0, 0);
  #pragma unroll
  for (int nt = 0; nt < 4; nt++)
    acc[1][nt] = __builtin_amdgcn_mfma_f32_16x16x32_f16(ah1, B.l[nt], acc[1][nt], 0, 0, 0);
  #pragma unroll
  for (int nt = 0; nt < 4; nt++)
    acc[0][nt] = __builtin_amdgcn_mfma_f32_16x16x32_f16(al0, B.h[nt], acc[0][nt], 0, 0, 0);
  #pragma unroll
  for (int nt = 0; nt < 4; nt++)
    acc[1][nt] = __builtin_amdgcn_mfma_f32_16x16x32_f16(al1, B.h[nt], acc[1][nt], 0, 0, 0);
}

// ---- 32x256 @ 256x256 split-fp16 MFMA, 2-deep static B pipeline (R25).
// B0 = kt0, preloaded by caller before the preceding epilogue (free drain
// at the entry barrier); refills go 2 kt ahead. Entry barrier makes the
// A-plane writes visible; callers must NOT sync before. ----
__device__ __forceinline__ void mfma_body(f32x4 acc[2][4], BF& B0,
    const _Float16* __restrict__ Ah, const _Float16* __restrict__ Al,
    const _Float16* __restrict__ Wh, const _Float16* __restrict__ Wl,
    int aoff, size_t boff) {
  BF B1;
  #pragma unroll
  for (int mt = 0; mt < 2; mt++)
    #pragma unroll
    for (int nt = 0; nt < 4; nt++)
      acc[mt][nt] = (f32x4){0.f, 0.f, 0.f, 0.f};
  __syncthreads();
  loadB<1>(B1, Wh, Wl, boff);
  computeKt<0>(acc, Ah, Al, aoff, B0);
  loadB<2>(B0, Wh, Wl, boff);
  computeKt<1>(acc, Ah, Al, aoff, B1);
  loadB<3>(B1, Wh, Wl, boff);
  computeKt<2>(acc, Ah, Al, aoff, B0);
  loadB<4>(B0, Wh, Wl, boff);
  computeKt<3>(acc, Ah, Al, aoff, B1);
  loadB<5>(B1, Wh, Wl, boff);
  computeKt<4>(acc, Ah, Al, aoff, B0);
  loadB<6>(B0, Wh, Wl, boff);
  computeKt<5>(acc, Ah, Al, aoff, B1);
  loadB<7>(B1, Wh, Wl, boff);
  computeKt<6>(acc, Ah, Al, aoff, B0);
  computeKt<7>(acc, Ah, Al, aoff, B1);
}

// ---- GN(32 groups x 8 chans)+SiLU from residual regs (C-layout) -> A ----
__device__ __forceinline__ void gn_x_to_A(const float x[2][4][4],
    const float* __restrict__ gnw, const float* __restrict__ gnb,
    int col, int quad, int nb,
    _Float16* __restrict__ Ah, _Float16* __restrict__ Al) {
  #pragma unroll
  for (int nt = 0; nt < 4; nt++) {
    int n = nb + (nt << 4) + col;
    float gwv = gnw[n], gbv = gnb[n];
    #pragma unroll
    for (int mt = 0; mt < 2; mt++) {
      #pragma unroll
      for (int rg = 0; rg < 4; rg++) {
        float v = x[mt][nt][rg];
        float s = gsum8(v);
        float q = gsum8(v * v);
        float mu = s * 0.125f;
        float rs = rsqrtf(q * 0.125f - mu * mu + 1e-5f);
        float y = (v - mu) * rs * gwv + gbv;
        float sv = y * sigm(y);
        hl_store(Ah, Al, ((mt << 4) + (quad << 2) + rg) * AS + n, sv);
      }
    }
  }
}

// ---- (acc + bias) -> GN+SiLU -> A, all in registers ----
__device__ __forceinline__ void epi_gn_to_A(const f32x4 acc[2][4],
    const float* __restrict__ bias,
    const float* __restrict__ gnw, const float* __restrict__ gnb,
    int col, int quad, int nb,
    _Float16* __restrict__ Ah, _Float16* __restrict__ Al) {
  #pragma unroll
  for (int nt = 0; nt < 4; nt++) {
    int n = nb + (nt << 4) + col;
    float bv = bias[n];
    float gwv = gnw[n], gbv = gnb[n];
    #pragma unroll
    for (int mt = 0; mt < 2; mt++) {
      #pragma unroll
      for (int rg = 0; rg < 4; rg++) {
        float v = acc[mt][nt][rg] + bv;
        float s = gsum8(v);
        float q = gsum8(v * v);
        float mu = s * 0.125f;
        float rs = rsqrtf(q * 0.125f - mu * mu + 1e-5f);
        float y = (v - mu) * rs * gwv + gbv;
        float sv = y * sigm(y);
        hl_store(Ah, Al, ((mt << 4) + (quad << 2) + rg) * AS + n, sv);
      }
    }
  }
}

// ---- relu(acc + bias) -> A ----
__device__ __forceinline__ void epi_relu_to_A(const f32x4 acc[2][4],
    const float* __restrict__ bias, int col, int quad, int nb,
    _Float16* __restrict__ Ah, _Float16* __restrict__ Al) {
  #pragma unroll
  for (int nt = 0; nt < 4; nt++) {
    int n = nb + (nt << 4) + col;
    float bv = bias[n];
    #pragma unroll
    for (int mt = 0; mt < 2; mt++)
      #pragma unroll
      for (int rg = 0; rg < 4; rg++)
        hl_store(Ah, Al, ((mt << 4) + (quad << 2) + rg) * AS + n,
                 fmaxf(acc[mt][nt][rg] + bv, 0.f));
  }
}

__global__ __launch_bounds__(256, 2) void fused_mfma(
    const float* __restrict__ gimage, const int* __restrict__ pts,
    const float* __restrict__ gn1w, const float* __restrict__ gn1b,
    const float* __restrict__ c1b,
    const float* __restrict__ gn2w, const float* __restrict__ gn2b,
    const float* __restrict__ c2b,
    const float* __restrict__ clsw, const float* __restrict__ clsb,
    const float* __restrict__ b1, const float* __restrict__ b2,
    const float* __restrict__ w3, const float* __restrict__ b3,
    const _Float16* __restrict__ ws, float* __restrict__ out) {
  __shared__ _Float16 Ah[2][32 * AS];   // activation hi, double-buffered
  __shared__ _Float16 Al[2][32 * AS];   // activation lo, double-buffered
  __shared__ float red[4][32][4];       // head reduction scratch

  const int t = threadIdx.x;
  const int w = t >> 6;
  const int lane = t & 63;
  const int col = lane & 15;
  const int quad = lane >> 4;
  const int nb = w << 6;              // wave's 64-col slab
  // XCD-chunked bijective swizzle (R20: FETCH 151->23MB)
  const int bsw = ((blockIdx.x & 7) << 8) | (blockIdx.x >> 3);
  const int row0 = bsw << 5;
  const int rbase = quad << 2;

  const int aoff = col * AS + (quad << 3);
  const size_t boff = (((size_t)(nb + col)) << 8) + (quad << 3);
  const _Float16* wsl = ws + NHALF;

  // ---- gather residual X directly into C-layout registers ----
  float x[2][4][4];
  {
    int lin[2][4];
    #pragma unroll
    for (int mt = 0; mt < 2; mt++)
      #pragma unroll
      for (int rg = 0; rg < 4; rg++) {
        int grow = row0 + (mt << 4) + rbase + rg;
        int p0 = pts[2 * grow], p1 = pts[2 * grow + 1];
        lin[mt][rg] = ((p0 >> 3) << 5) + (p1 >> 3);
      }
    const float* gbase = gimage + (((size_t)((row0 >> 11) << 8)) << 10);
    #pragma unroll
    for (int nt = 0; nt < 4; nt++) {
      const float* gc = gbase + (((size_t)(nb + (nt << 4) + col)) << 10);
      #pragma unroll
      for (int mt = 0; mt < 2; mt++)
        #pragma unroll
        for (int rg = 0; rg < 4; rg++)
          x[mt][nt][rg] = gc[lin[mt][rg]];
    }
  }

  f32x4 acc[2][4];
  BF B;

  // ---- 2x ResBlock; writers alternate planes (gn_x->0, epi_gn->1);
  // every epilogue writes the plane the NEXT GEMM reads; the only barrier
  // is each mfma_body's entry barrier. B0 issued one epilogue ahead. ----
  loadB<0>(B, ws + OFF_WC1, wsl + OFF_WC1, boff);
  #pragma unroll 1
  for (int rb = 0; rb < 2; rb++) {
    gn_x_to_A(x, gn1w + (rb << 8), gn1b + (rb << 8), col, quad, nb,
              Ah[0], Al[0]);
    mfma_body(acc, B, Ah[0], Al[0], ws + OFF_WC1 + (rb << 16),
              wsl + OFF_WC1 + (rb << 16), aoff, boff);
    loadB<0>(B, ws + OFF_WC2 + (rb << 16), wsl + OFF_WC2 + (rb << 16), boff);
    epi_gn_to_A(acc, c1b + (rb << 8), gn2w + (rb << 8), gn2b + (rb << 8),
                col, quad, nb, Ah[1], Al[1]);
    mfma_body(acc, B, Ah[1], Al[1], ws + OFF_WC2 + (rb << 16),
              wsl + OFF_WC2 + (rb << 16), aoff, boff);
    if (rb == 0)
      loadB<0>(B, ws + OFF_WC1 + 65536, wsl + OFF_WC1 + 65536, boff);
    else
      loadB<0>(B, ws + OFF_W1, wsl + OFF_W1, boff);
    #pragma unroll
    for (int nt = 0; nt < 4; nt++) {
      float bv = c2b[(rb << 8) + nb + (nt << 4) + col];
      #pragma unroll
      for (int mt = 0; mt < 2; mt++)
        #pragma unroll
        for (int rg = 0; rg < 4; rg++)
          x[mt][nt][rg] += acc[mt][nt][rg] + bv;
    }
  }

  // ---- A[0] = hl(x) for the MLP; cls partials from x (regs) ----
  #pragma unroll
  for (int nt = 0; nt < 4; nt++) {
    int n = nb + (nt << 4) + col;
    #pragma unroll
    for (int mt = 0; mt < 2; mt++)
      #pragma unroll
      for (int rg = 0; rg < 4; rg++)
        hl_store(Ah[0], Al[0], ((mt << 4) + rbase + rg) * AS + n,
                 x[mt][nt][rg]);
  }
  {
    float pc[2][2][4];
    #pragma unroll
    for (int j = 0; j < 2; j++) {
      #pragma unroll
      for (int mt = 0; mt < 2; mt++)
        #pragma unroll
        for (int rg = 0; rg < 4; rg++)
          pc[j][mt][rg] = 0.f;
      #pragma unroll
      for (int nt = 0; nt < 4; nt++) {
        float wv = clsw[(j << 8) + nb + (nt << 4) + col];
        #pragma unroll
        for (int mt = 0; mt < 2; mt++)
          #pragma unroll
          for (int rg = 0; rg < 4; rg++)
            pc[j][mt][rg] += x[mt][nt][rg] * wv;
      }
    }
    #pragma unroll
    for (int j = 0; j < 2; j++)
      #pragma unroll
      for (int mt = 0; mt < 2; mt++)
        #pragma unroll
        for (int rg = 0; rg < 4; rg++) {
          float p = gsum16(pc[j][mt][rg]);
          if (col == 0) red[w][(mt << 4) + rbase + rg][j] = p;
        }
  }

  // ---- MLP gemm1 (w1); cls finalize rides alongside ----
  mfma_body(acc, B, Ah[0], Al[0], ws + OFF_W1, wsl + OFF_W1, aoff, boff);
  if (t < 64) {
    int r = t >> 1, j = t & 1;
    out[((size_t)(row0 + r) << 1) + j] =
        clsb[j] + red[0][r][j] + red[1][r][j] + red[2][r][j] + red[3][r][j];
  }
  loadB<0>(B, ws + OFF_W2, wsl + OFF_W2, boff);
  epi_relu_to_A(acc, b1, col, quad, nb, Ah[1], Al[1]);

  // ---- MLP gemm2 (w2) -> relu -> w3 partials in regs ----
  mfma_body(acc, B, Ah[1], Al[1], ws + OFF_W2, wsl + OFF_W2, aoff, boff);
  {
    float pb[4][2][4];
    #pragma unroll
    for (int j = 0; j < 4; j++)
      #pragma unroll
      for (int mt = 0; mt < 2; mt++)
        #pragma unroll
        for (int rg = 0; rg < 4; rg++)
          pb[j][mt][rg] = 0.f;
    #pragma unroll
    for (int nt = 0; nt < 4; nt++) {
      int n = nb + (nt << 4) + col;
      float bv = b2[n];
      float w0 = w3[n], w1v = w3[256 + n], w2v = w3[512 + n], w3v = w3[768 + n];
      #pragma unroll
      for (int mt = 0; mt < 2; mt++)
        #pragma unroll
        for (int rg = 0; rg < 4; rg++) {
          float v = fmaxf(acc[mt][nt][rg] + bv, 0.f);
          pb[0][mt][rg] += v * w0;
          pb[1][mt][rg] += v * w1v;
          pb[2][mt][rg] += v * w2v;
          pb[3][mt][rg] += v * w3v;
        }
    }
    #pragma unroll
    for (int j = 0; j < 4; j++)
      #pragma unroll
      for (int mt = 0; mt < 2; mt++)
        #pragma unroll
        for (int rg = 0; rg < 4; rg++) {
          float p = gsum16(pb[j][mt][rg]);
          if (col == 0) red[w][(mt << 4) + rbase + rg][j] = p;
        }
  }
  __syncthreads();
  if (t < 128) {
    int r = t >> 2, j = t & 3;
    float s = b3[j] + red[0][r][j] + red[1][r][j] + red[2][r][j] + red[3][r][j];
    out[131072 + ((size_t)(row0 + r) << 2) + j] = sigm(s);
  }
}

// ================= fp32 fallback (R11, proven) for tiny ws =================
#define LS 260
template <int EPI, bool CONV>
__device__ __forceinline__ void gemm_f32(const float* __restrict__ src,
                                         const float* __restrict__ W,
                                         const float* __restrict__ bias,
                                         float* __restrict__ dst,
                                         float* __restrict__ X) {
  const int n = threadIdx.x;
  float acc[32];
  #pragma unroll
  for (int r = 0; r < 32; r++) acc[r] = 0.f;
  #pragma unroll 1
  for (int k = 0; k < 256; k += 8) {
    float w[8];
    if (CONV) {
      #pragma unroll
      for (int j = 0; j < 8; j++) w[j] = W[(size_t)((n << 8) + k + j) * 9 + 4];
    } else {
      f32x4 wa = *(const f32x4*)(W + (n << 8) + k);
      f32x4 wb = *(const f32x4*)(W + (n << 8) + k + 4);
      w[0] = wa[0]; w[1] = wa[1]; w[2] = wa[2]; w[3] = wa[3];
      w[4] = wb[0]; w[5] = wb[1]; w[6] = wb[2]; w[7] = wb[3];
    }
    #pragma unroll
    for (int r = 0; r < 32; r++) {
      const float* xr = src + r * LS + k;
      f32x4 a0 = *(const f32x4*)xr, a1 = *(const f32x4*)(xr + 4);
      acc[r] += a0[0] * w[0] + a0[1] * w[1] + a0[2] * w[2] + a0[3] * w[3]
              + a1[0] * w[4] + a1[1] * w[5] + a1[2] * w[6] + a1[3] * w[7];
    }
  }
  float bv = bias[n];
  #pragma unroll
  for (int r = 0; r < 32; r++) {
    float v = acc[r] + bv;
    if (EPI == 0) dst[r * LS + n] = v;
    else if (EPI == 1) X[r * LS + n] += v;
    else dst[r * LS + n] = fmaxf(v, 0.f);
  }
}
__device__ __forceinline__ void gn_silu32(const float* __restrict__ src,
                                          float* __restrict__ dst,
                                          const float* __restrict__ gw,
                                          const float* __restrict__ gb, int t) {
  #pragma unroll
  for (int i = 0; i < 4; i++) {
    int task = (i << 8) + t;
    int r = task >> 5, g = task & 31;
    const float* x = src + r * LS + (g << 3);
    f32x4 x0 = *(const f32x4*)x, x1 = *(const f32x4*)(x + 4);
    float xx[8] = {x0[0], x0[1], x0[2], x0[3], x1[0], x1[1], x1[2], x1[3]};
    float s = 0.f, q = 0.f;
    #pragma unroll
    for (int j = 0; j < 8; j++) { s += xx[j]; q += xx[j] * xx[j]; }
    float mu = s * 0.125f;
    float rs = rsqrtf(q * 0.125f - mu * mu + 1e-5f);
    const float* w = gw + (g << 3);
    const float* b = gb + (g << 3);
    float* d = dst + r * LS + (g << 3);
    #pragma unroll
    for (int j = 0; j < 8; j++) {
      float y = (xx[j] - mu) * rs * w[j] + b[j];
      d[j] = y * sigm(y);
    }
  }
}
__global__ __launch_bounds__(256, 1) void fused_all(
    const float* __restrict__ gimage, const int* __restrict__ pts,
    const float* __restrict__ gn1w, const float* __restrict__ gn1b,
    const float* __restrict__ c1w, const float* __restrict__ c1b,
    const float* __restrict__ gn2w, const float* __restrict__ gn2b,
    const float* __restrict__ c2w, const float* __restrict__ c2b,
    const float* __restrict__ clsw, const float* __restrict__ clsb,
    const float* __restrict__ w1, const float* __restrict__ b1,
    const float* __restrict__ w2, const float* __restrict__ b2,
    const float* __restrict__ w3, const float* __restrict__ b3,
    float* __restrict__ out) {
  __shared__ float X[32 * LS];
  __shared__ float A[32 * LS];
  __shared__ float H[32 * LS];
  const int t = threadIdx.x;
  const int row0 = blockIdx.x << 5;
  {
    int r = t >> 3;
    int c0 = (t & 7) << 5;
    int grow = row0 + r;
    int p0 = pts[2 * grow], p1 = pts[2 * grow + 1];
    int lin = ((p0 >> 3) << 5) + (p1 >> 3);
    int b = grow >> 11;
    const float* src = gimage + (((size_t)((b << 8) + c0)) << 10) + lin;
    #pragma unroll
    for (int c = 0; c < 32; c++) X[r * LS + c0 + c] = src[(size_t)c << 10];
  }
  __syncthreads();
  #pragma unroll 1
  for (int rb = 0; rb < 2; rb++) {
    gn_silu32(X, A, gn1w + (rb << 8), gn1b + (rb << 8), t);
    __syncthreads();
    gemm_f32<0, true>(A, c1w + rb * 589824, c1b + (rb << 8), H, nullptr);
    __syncthreads();
    gn_silu32(H, A, gn2w + (rb << 8), gn2b + (rb << 8), t);
    __syncthreads();
    gemm_f32<1, true>(A, c2w + rb * 589824, c2b + (rb << 8), nullptr, X);
    __syncthreads();
  }
  if (t < 64) {
    int r = t >> 1, j = t & 1;
    float s = clsb[j];
    const float* w = clsw + (j << 8);
    const float* x = X + r * LS;
    #pragma unroll 1
    for (int k = 0; k < 256; k += 4) {
      f32x4 wv = *(const f32x4*)(w + k);
      f32x4 xv = *(const f32x4*)(x + k);
      s += xv[0] * wv[0] + xv[1] * wv[1] + xv[2] * wv[2] + xv[3] * wv[3];
    }
    out[((size_t)(row0 + r) << 1) + j] = s;
  }
  gemm_f32<2, false>(X, w1, b1, H, nullptr);
  __syncthreads();
  gemm_f32<2, false>(H, w2, b2, A, nullptr);
  __syncthreads();
  if (t < 128) {
    int r = t >> 2, j = t & 3;
    float s = b3[j];
    const float* w = w3 + (j << 8);
    const float* x = A + r * LS;
    #pragma unroll 1
    for (int k = 0; k < 256; k += 4) {
      f32x4 wv = *(const f32x4*)(w + k);
      f32x4 xv = *(const f32x4*)(x + k);
      s += xv[0] * wv[0] + xv[1] * wv[1] + xv[2] * wv[2] + xv[3] * wv[3];
    }
    out[131072 + ((size_t)(row0 + r) << 2) + j] = sigm(s);
  }
}

extern "C" void kernel_launch(void* const* d_in, const int* in_sizes, int n_in,
                              void* d_out, int out_size, void* d_ws, size_t ws_size,
                              hipStream_t stream) {
  const float* gimage = (const float*)d_in[0];
  const int* pts = (const int*)d_in[1];
  const float* gn1w = (const float*)d_in[2];
  const float* gn1b = (const float*)d_in[3];
  const float* c1w = (const float*)d_in[4];
  const float* c1b = (const float*)d_in[5];
  const float* gn2w = (const float*)d_in[6];
  const float* gn2b = (const float*)d_in[7];
  const float* c2w = (const float*)d_in[8];
  const float* c2b = (const float*)d_in[9];
  const float* clsw = (const float*)d_in[10];
  const float* clsb = (const float*)d_in[11];
  const float* w1 = (const float*)d_in[12];
  const float* b1 = (const float*)d_in[13];
  const float* w2 = (const float*)d_in[14];
  const float* b2 = (const float*)d_in[15];
  const float* w3 = (const float*)d_in[16];
  const float* b3 = (const float*)d_in[17];

  if (ws_size >= (size_t)WS_NEED) {
    _Float16* ws = (_Float16*)d_ws;
    prep<<<512, 256, 0, stream>>>(c1w, c2w, w1, w2, ws);
    fused_mfma<<<2048, 256, 0, stream>>>(gimage, pts, gn1w, gn1b, c1b,
                                         gn2w, gn2b, c2b, clsw, clsb,
                                         b1, b2, w3, b3, ws, (float*)d_out);
  } else {
    fused_all<<<2048, 256, 0, stream>>>(gimage, pts, gn1w, gn1b, c1w, c1b,
                                        gn2w, gn2b, c2w, c2b, clsw, clsb,
                                        w1, b1, w2, b2, w3, b3, (float*)d_out);
  }
}

// Round 14
// 501.885 us; speedup vs baseline: 1.0678x; 1.0678x over previous
//
#include <hip/hip_runtime.h>

// Round 28: restore champion R24 (447us) + s_setprio(1) around MFMA chain.
// R27 post-mortem: 2-deep B compiled clean (no spill, VGPR 100) and still
// lost to R24 (477 vs 447) -> per-kt B latency refuted as a bottleneck;
// A-dbuf/2-block configs strictly worse. Ledger: every structural lever
// (occupancy, phases, NT, locality, B depth x3, barrier halving) tried;
// champion = R24 (preload-before-epilogue + DPP, 3 blk/CU, 12 barriers).
// This round reverts to R24 verbatim + T5 setprio around the kt chain:
// 3 co-resident blocks sit at DIFFERENT phases (not m190's lockstep null
// regime), so the scheduler can favor MFMA-cluster waves. Bit-identical
// numerics (absmax 0.0078125). fp32 fallback (R11) retained for tiny ws.

typedef __attribute__((ext_vector_type(8))) _Float16 half8;
typedef __attribute__((ext_vector_type(4))) float f32x4;

#define AS 264   // fp16 A stride (+8 pad)

#define NHALF  393216    // elements per precision plane in ws
#define OFF_WC1 0        // [2][256][256]
#define OFF_WC2 131072
#define OFF_W1  262144   // [256][256]
#define OFF_W2  327680
#define WS_NEED 1572864  // bytes = 2 planes x 393216 halves x 2B

__device__ __forceinline__ float sigm(float y) { return 1.f / (1.f + __expf(-y)); }

// ---- DPP lane-sum helper (R24 proven): v + perm(v), within 16-lane row ----
template <int CTRL>
__device__ __forceinline__ float dppadd(float v) {
  union { float f; int i; } u, r;
  u.f = v;
  r.i = __builtin_amdgcn_update_dpp(0, u.i, CTRL, 0xf, 0xf, true);
  return v + r.f;
}
#define DPP_X1 0xB1   // quad_perm [1,0,3,2]  == lane^1
#define DPP_X2 0x4E   // quad_perm [2,3,0,1]  == lane^2
#define DPP_X7 0x141  // row_half_mirror      == lane^7 (quad-sum partner)
#define DPP_XF 0x140  // row_mirror           == lane^15 (8-group partner)

__device__ __forceinline__ float gsum8(float v) {
  v = dppadd<DPP_X1>(v);
  v = dppadd<DPP_X2>(v);
  v = dppadd<DPP_X7>(v);
  return v;
}
__device__ __forceinline__ float gsum16(float v) {
  v = dppadd<DPP_X1>(v);
  v = dppadd<DPP_X2>(v);
  v = dppadd<DPP_X7>(v);
  v = dppadd<DPP_XF>(v);
  return v;
}

// ---- prep: pack weights as fp16 hi/lo planes: wsl = wsh + NHALF ----
__global__ __launch_bounds__(256) void prep(const float* __restrict__ c1w,
                                            const float* __restrict__ c2w,
                                            const float* __restrict__ w1,
                                            const float* __restrict__ w2,
                                            _Float16* __restrict__ ws) {
  int i = blockIdx.x * 256 + threadIdx.x;  // 0..131071
  {
    float v = c1w[(size_t)i * 9 + 4];
    _Float16 h = (_Float16)v;
    ws[OFF_WC1 + i] = h;
    ws[NHALF + OFF_WC1 + i] = (_Float16)(v - (float)h);
  }
  {
    float v = c2w[(size_t)i * 9 + 4];
    _Float16 h = (_Float16)v;
    ws[OFF_WC2 + i] = h;
    ws[NHALF + OFF_WC2 + i] = (_Float16)(v - (float)h);
  }
  if (i < 65536) {
    float v = w1[i];
    _Float16 h = (_Float16)v;
    ws[OFF_W1 + i] = h;
    ws[NHALF + OFF_W1 + i] = (_Float16)(v - (float)h);
    v = w2[i];
    h = (_Float16)v;
    ws[OFF_W2 + i] = h;
    ws[NHALF + OFF_W2 + i] = (_Float16)(v - (float)h);
  }
}

// ---- hi/lo split store into A planes ----
__device__ __forceinline__ void hl_store(_Float16* __restrict__ Ah,
                                         _Float16* __restrict__ Al,
                                         int idx, float v) {
  _Float16 h = (_Float16)v;
  Ah[idx] = h;
  Al[idx] = (_Float16)(v - (float)h);
}

// ---- B fragment registers (kt=0 batch), preloaded EARLY so the loads
// complete during the preceding epilogue's VALU work; the barrier's
// vmcnt(0) drain is then ~free. ----
struct BF { half8 h[4], l[4]; };

__device__ __forceinline__ void preloadB(BF& B,
    const _Float16* __restrict__ Wh, const _Float16* __restrict__ Wl,
    size_t boff) {
  #pragma unroll
  for (int nt = 0; nt < 4; nt++) {
    B.h[nt] = *(const half8*)(Wh + boff + (nt << 12));
    B.l[nt] = *(const half8*)(Wl + boff + (nt << 12));
  }
}

// ---- 32x256 @ 256x256 split-fp16 MFMA (R24 proven): consumes preloaded
// kt=0 B batch, refills per-kt (1-deep). setprio(1) across the kt chain
// biases the CU scheduler toward this wave's MFMA cluster while other
// co-resident blocks (different phases) issue loads/epilogues.
// Callers must NOT sync before. ----
__device__ __forceinline__ void mfma_body(f32x4 acc[2][4], BF& B,
    const _Float16* __restrict__ Ah, const _Float16* __restrict__ Al,
    const _Float16* __restrict__ Wh, const _Float16* __restrict__ Wl,
    int aoff, size_t boff) {
  #pragma unroll
  for (int mt = 0; mt < 2; mt++)
    #pragma unroll
    for (int nt = 0; nt < 4; nt++)
      acc[mt][nt] = (f32x4){0.f, 0.f, 0.f, 0.f};
  __syncthreads();
  __builtin_amdgcn_s_setprio(1);
  #pragma unroll
  for (int kt = 0; kt < 8; kt++) {
    half8 ah0 = *(const half8*)(Ah + aoff + kt * 32);
    half8 ah1 = *(const half8*)(Ah + aoff + 16 * AS + kt * 32);
    half8 al0 = *(const half8*)(Al + aoff + kt * 32);
    half8 al1 = *(const half8*)(Al + aoff + 16 * AS + kt * 32);
    #pragma unroll
    for (int nt = 0; nt < 4; nt++) {
      acc[0][nt] = __builtin_amdgcn_mfma_f32_16x16x32_f16(ah0, B.h[nt], acc[0][nt], 0, 0, 0);
      acc[1][nt] = __builtin_amdgcn_mfma_f32_16x16x32_f16(ah1, B.h[nt], acc[1][nt], 0, 0, 0);
      acc[0][nt] = __builtin_amdgcn_mfma_f32_16x16x32_f16(ah0, B.l[nt], acc[0][nt], 0, 0, 0);
      acc[1][nt] = __builtin_amdgcn_mfma_f32_16x16x32_f16(ah1, B.l[nt], acc[1][nt], 0, 0, 0);
      acc[0][nt] = __builtin_amdgcn_mfma_f32_16x16x32_f16(al0, B.h[nt], acc[0][nt], 0, 0, 0);
      acc[1][nt] = __builtin_amdgcn_mfma_f32_16x16x32_f16(al1, B.h[nt], acc[1][nt], 0, 0, 0);
    }
    if (kt < 7) {
      #pragma unroll
      for (int nt = 0; nt < 4; nt++) {
        B.h[nt] = *(const half8*)(Wh + boff + (nt << 12) + (kt + 1) * 32);
        B.l[nt] = *(const half8*)(Wl + boff + (nt << 12) + (kt + 1) * 32);
      }
    }
  }
  __builtin_amdgcn_s_setprio(0);
}

// ---- GN(32 groups x 8 chans)+SiLU from residual regs (C-layout) -> A ----
__device__ __forceinline__ void gn_x_to_A(const float x[2][4][4],
    const float* __restrict__ gnw, const float* __restrict__ gnb,
    int col, int quad, int nb,
    _Float16* __restrict__ Ah, _Float16* __restrict__ Al) {
  #pragma unroll
  for (int nt = 0; nt < 4; nt++) {
    int n = nb + (nt << 4) + col;
    float gwv = gnw[n], gbv = gnb[n];
    #pragma unroll
    for (int mt = 0; mt < 2; mt++) {
      #pragma unroll
      for (int rg = 0; rg < 4; rg++) {
        float v = x[mt][nt][rg];
        float s = gsum8(v);
        float q = gsum8(v * v);
        float mu = s * 0.125f;
        float rs = rsqrtf(q * 0.125f - mu * mu + 1e-5f);
        float y = (v - mu) * rs * gwv + gbv;
        float sv = y * sigm(y);
        hl_store(Ah, Al, ((mt << 4) + (quad << 2) + rg) * AS + n, sv);
      }
    }
  }
}

// ---- (acc + bias) -> GN+SiLU -> A, all in registers ----
__device__ __forceinline__ void epi_gn_to_A(const f32x4 acc[2][4],
    const float* __restrict__ bias,
    const float* __restrict__ gnw, const float* __restrict__ gnb,
    int col, int quad, int nb,
    _Float16* __restrict__ Ah, _Float16* __restrict__ Al) {
  #pragma unroll
  for (int nt = 0; nt < 4; nt++) {
    int n = nb + (nt << 4) + col;
    float bv = bias[n];
    float gwv = gnw[n], gbv = gnb[n];
    #pragma unroll
    for (int mt = 0; mt < 2; mt++) {
      #pragma unroll
      for (int rg = 0; rg < 4; rg++) {
        float v = acc[mt][nt][rg] + bv;
        float s = gsum8(v);
        float q = gsum8(v * v);
        float mu = s * 0.125f;
        float rs = rsqrtf(q * 0.125f - mu * mu + 1e-5f);
        float y = (v - mu) * rs * gwv + gbv;
        float sv = y * sigm(y);
        hl_store(Ah, Al, ((mt << 4) + (quad << 2) + rg) * AS + n, sv);
      }
    }
  }
}

// ---- relu(acc + bias) -> A ----
__device__ __forceinline__ void epi_relu_to_A(const f32x4 acc[2][4],
    const float* __restrict__ bias, int col, int quad, int nb,
    _Float16* __restrict__ Ah, _Float16* __restrict__ Al) {
  #pragma unroll
  for (int nt = 0; nt < 4; nt++) {
    int n = nb + (nt << 4) + col;
    float bv = bias[n];
    #pragma unroll
    for (int mt = 0; mt < 2; mt++)
      #pragma unroll
      for (int rg = 0; rg < 4; rg++)
        hl_store(Ah, Al, ((mt << 4) + (quad << 2) + rg) * AS + n,
                 fmaxf(acc[mt][nt][rg] + bv, 0.f));
  }
}

__global__ __launch_bounds__(256, 3) void fused_mfma(
    const float* __restrict__ gimage, const int* __restrict__ pts,
    const float* __restrict__ gn1w, const float* __restrict__ gn1b,
    const float* __restrict__ c1b,
    const float* __restrict__ gn2w, const float* __restrict__ gn2b,
    const float* __restrict__ c2b,
    const float* __restrict__ clsw, const float* __restrict__ clsb,
    const float* __restrict__ b1, const float* __restrict__ b2,
    const float* __restrict__ w3, const float* __restrict__ b3,
    const _Float16* __restrict__ ws, float* __restrict__ out) {
  __shared__ _Float16 Ah[32 * AS];    // activation hi
  __shared__ _Float16 Al[32 * AS];    // activation lo
  __shared__ float red[4][32][4];     // head reduction scratch

  const int t = threadIdx.x;
  const int w = t >> 6;
  const int lane = t & 63;
  const int col = lane & 15;
  const int quad = lane >> 4;
  const int nb = w << 6;              // wave's 64-col slab
  // XCD-chunked bijective swizzle (R20: FETCH 151->23MB)
  const int bsw = ((blockIdx.x & 7) << 8) | (blockIdx.x >> 3);
  const int row0 = bsw << 5;
  const int rbase = quad << 2;

  const int aoff = col * AS + (quad << 3);
  const size_t boff = (((size_t)(nb + col)) << 8) + (quad << 3);
  const _Float16* wsl = ws + NHALF;

  // ---- gather residual X directly into C-layout registers ----
  float x[2][4][4];
  {
    int lin[2][4];
    #pragma unroll
    for (int mt = 0; mt < 2; mt++)
      #pragma unroll
      for (int rg = 0; rg < 4; rg++) {
        int grow = row0 + (mt << 4) + rbase + rg;
        int p0 = pts[2 * grow], p1 = pts[2 * grow + 1];
        lin[mt][rg] = ((p0 >> 3) << 5) + (p1 >> 3);
      }
    const float* gbase = gimage + (((size_t)((row0 >> 11) << 8)) << 10);
    #pragma unroll
    for (int nt = 0; nt < 4; nt++) {
      const float* gc = gbase + (((size_t)(nb + (nt << 4) + col)) << 10);
      #pragma unroll
      for (int mt = 0; mt < 2; mt++)
        #pragma unroll
        for (int rg = 0; rg < 4; rg++)
          x[mt][nt][rg] = gc[lin[mt][rg]];
    }
  }

  f32x4 acc[2][4];
  BF B;

  // ---- 2x ResBlock; B batches issued one epilogue ahead ----
  preloadB(B, ws + OFF_WC1, wsl + OFF_WC1, boff);
  #pragma unroll 1
  for (int rb = 0; rb < 2; rb++) {
    gn_x_to_A(x, gn1w + (rb << 8), gn1b + (rb << 8), col, quad, nb, Ah, Al);
    mfma_body(acc, B, Ah, Al, ws + OFF_WC1 + (rb << 16),
              wsl + OFF_WC1 + (rb << 16), aoff, boff);
    __syncthreads();
    preloadB(B, ws + OFF_WC2 + (rb << 16), wsl + OFF_WC2 + (rb << 16), boff);
    epi_gn_to_A(acc, c1b + (rb << 8), gn2w + (rb << 8), gn2b + (rb << 8),
                col, quad, nb, Ah, Al);
    mfma_body(acc, B, Ah, Al, ws + OFF_WC2 + (rb << 16),
              wsl + OFF_WC2 + (rb << 16), aoff, boff);
    __syncthreads();
    if (rb == 0)
      preloadB(B, ws + OFF_WC1 + 65536, wsl + OFF_WC1 + 65536, boff);
    else
      preloadB(B, ws + OFF_W1, wsl + OFF_W1, boff);
    #pragma unroll
    for (int nt = 0; nt < 4; nt++) {
      float bv = c2b[(rb << 8) + nb + (nt << 4) + col];
      #pragma unroll
      for (int mt = 0; mt < 2; mt++)
        #pragma unroll
        for (int rg = 0; rg < 4; rg++)
          x[mt][nt][rg] += acc[mt][nt][rg] + bv;
    }
  }

  // ---- A = hl(x) for the MLP; cls partials from x (regs) ----
  #pragma unroll
  for (int nt = 0; nt < 4; nt++) {
    int n = nb + (nt << 4) + col;
    #pragma unroll
    for (int mt = 0; mt < 2; mt++)
      #pragma unroll
      for (int rg = 0; rg < 4; rg++)
        hl_store(Ah, Al, ((mt << 4) + rbase + rg) * AS + n, x[mt][nt][rg]);
  }
  {
    float pc[2][2][4];
    #pragma unroll
    for (int j = 0; j < 2; j++) {
      #pragma unroll
      for (int mt = 0; mt < 2; mt++)
        #pragma unroll
        for (int rg = 0; rg < 4; rg++)
          pc[j][mt][rg] = 0.f;
      #pragma unroll
      for (int nt = 0; nt < 4; nt++) {
        float wv = clsw[(j << 8) + nb + (nt << 4) + col];
        #pragma unroll
        for (int mt = 0; mt < 2; mt++)
          #pragma unroll
          for (int rg = 0; rg < 4; rg++)
            pc[j][mt][rg] += x[mt][nt][rg] * wv;
      }
    }
    #pragma unroll
    for (int j = 0; j < 2; j++)
      #pragma unroll
      for (int mt = 0; mt < 2; mt++)
        #pragma unroll
        for (int rg = 0; rg < 4; rg++) {
          float p = gsum16(pc[j][mt][rg]);
          if (col == 0) red[w][(mt << 4) + rbase + rg][j] = p;
        }
  }

  // ---- MLP gemm1 (w1); cls finalize rides alongside ----
  mfma_body(acc, B, Ah, Al, ws + OFF_W1, wsl + OFF_W1, aoff, boff);
  if (t < 64) {
    int r = t >> 1, j = t & 1;
    out[((size_t)(row0 + r) << 1) + j] =
        clsb[j] + red[0][r][j] + red[1][r][j] + red[2][r][j] + red[3][r][j];
  }
  __syncthreads();
  preloadB(B, ws + OFF_W2, wsl + OFF_W2, boff);
  epi_relu_to_A(acc, b1, col, quad, nb, Ah, Al);

  // ---- MLP gemm2 (w2) -> relu -> w3 partials in regs ----
  mfma_body(acc, B, Ah, Al, ws + OFF_W2, wsl + OFF_W2, aoff, boff);
  __syncthreads();
  {
    float pb[4][2][4];
    #pragma unroll
    for (int j = 0; j < 4; j++)
      #pragma unroll
      for (int mt = 0; mt < 2; mt++)
        #pragma unroll
        for (int rg = 0; rg < 4; rg++)
          pb[j][mt][rg] = 0.f;
    #pragma unroll
    for (int nt = 0; nt < 4; nt++) {
      int n = nb + (nt << 4) + col;
      float bv = b2[n];
      float w0 = w3[n], w1v = w3[256 + n], w2v = w3[512 + n], w3v = w3[768 + n];
      #pragma unroll
      for (int mt = 0; mt < 2; mt++)
        #pragma unroll
        for (int rg = 0; rg < 4; rg++) {
          float v = fmaxf(acc[mt][nt][rg] + bv, 0.f);
          pb[0][mt][rg] += v * w0;
          pb[1][mt][rg] += v * w1v;
          pb[2][mt][rg] += v * w2v;
          pb[3][mt][rg] += v * w3v;
        }
    }
    #pragma unroll
    for (int j = 0; j < 4; j++)
      #pragma unroll
      for (int mt = 0; mt < 2; mt++)
        #pragma unroll
        for (int rg = 0; rg < 4; rg++) {
          float p = gsum16(pb[j][mt][rg]);
          if (col == 0) red[w][(mt << 4) + rbase + rg][j] = p;
        }
  }
  __syncthreads();
  if (t < 128) {
    int r = t >> 2, j = t & 3;
    float s = b3[j] + red[0][r][j] + red[1][r][j] + red[2][r][j] + red[3][r][j];
    out[131072 + ((size_t)(row0 + r) << 2) + j] = sigm(s);
  }
}

// ================= fp32 fallback (R11, proven) for tiny ws =================
#define LS 260
template <int EPI, bool CONV>
__device__ __forceinline__ void gemm_f32(const float* __restrict__ src,
                                         const float* __restrict__ W,
                                         const float* __restrict__ bias,
                                         float* __restrict__ dst,
                                         float* __restrict__ X) {
  const int n = threadIdx.x;
  float acc[32];
  #pragma unroll
  for (int r = 0; r < 32; r++) acc[r] = 0.f;
  #pragma unroll 1
  for (int k = 0; k < 256; k += 8) {
    float w[8];
    if (CONV) {
      #pragma unroll
      for (int j = 0; j < 8; j++) w[j] = W[(size_t)((n << 8) + k + j) * 9 + 4];
    } else {
      f32x4 wa = *(const f32x4*)(W + (n << 8) + k);
      f32x4 wb = *(const f32x4*)(W + (n << 8) + k + 4);
      w[0] = wa[0]; w[1] = wa[1]; w[2] = wa[2]; w[3] = wa[3];
      w[4] = wb[0]; w[5] = wb[1]; w[6] = wb[2]; w[7] = wb[3];
    }
    #pragma unroll
    for (int r = 0; r < 32; r++) {
      const float* xr = src + r * LS + k;
      f32x4 a0 = *(const f32x4*)xr, a1 = *(const f32x4*)(xr + 4);
      acc[r] += a0[0] * w[0] + a0[1] * w[1] + a0[2] * w[2] + a0[3] * w[3]
              + a1[0] * w[4] + a1[1] * w[5] + a1[2] * w[6] + a1[3] * w[7];
    }
  }
  float bv = bias[n];
  #pragma unroll
  for (int r = 0; r < 32; r++) {
    float v = acc[r] + bv;
    if (EPI == 0) dst[r * LS + n] = v;
    else if (EPI == 1) X[r * LS + n] += v;
    else dst[r * LS + n] = fmaxf(v, 0.f);
  }
}
__device__ __forceinline__ void gn_silu32(const float* __restrict__ src,
                                          float* __restrict__ dst,
                                          const float* __restrict__ gw,
                                          const float* __restrict__ gb, int t) {
  #pragma unroll
  for (int i = 0; i < 4; i++) {
    int task = (i << 8) + t;
    int r = task >> 5, g = task & 31;
    const float* x = src + r * LS + (g << 3);
    f32x4 x0 = *(const f32x4*)x, x1 = *(const f32x4*)(x + 4);
    float xx[8] = {x0[0], x0[1], x0[2], x0[3], x1[0], x1[1], x1[2], x1[3]};
    float s = 0.f, q = 0.f;
    #pragma unroll
    for (int j = 0; j < 8; j++) { s += xx[j]; q += xx[j] * xx[j]; }
    float mu = s * 0.125f;
    float rs = rsqrtf(q * 0.125f - mu * mu + 1e-5f);
    const float* w = gw + (g << 3);
    const float* b = gb + (g << 3);
    float* d = dst + r * LS + (g << 3);
    #pragma unroll
    for (int j = 0; j < 8; j++) {
      float y = (xx[j] - mu) * rs * w[j] + b[j];
      d[j] = y * sigm(y);
    }
  }
}
__global__ __launch_bounds__(256, 1) void fused_all(
    const float* __restrict__ gimage, const int* __restrict__ pts,
    const float* __restrict__ gn1w, const float* __restrict__ gn1b,
    const float* __restrict__ c1w, const float* __restrict__ c1b,
    const float* __restrict__ gn2w, const float* __restrict__ gn2b,
    const float* __restrict__ c2w, const float* __restrict__ c2b,
    const float* __restrict__ clsw, const float* __restrict__ clsb,
    const float* __restrict__ w1, const float* __restrict__ b1,
    const float* __restrict__ w2, const float* __restrict__ b2,
    const float* __restrict__ w3, const float* __restrict__ b3,
    float* __restrict__ out) {
  __shared__ float X[32 * LS];
  __shared__ float A[32 * LS];
  __shared__ float H[32 * LS];
  const int t = threadIdx.x;
  const int row0 = blockIdx.x << 5;
  {
    int r = t >> 3;
    int c0 = (t & 7) << 5;
    int grow = row0 + r;
    int p0 = pts[2 * grow], p1 = pts[2 * grow + 1];
    int lin = ((p0 >> 3) << 5) + (p1 >> 3);
    int b = grow >> 11;
    const float* src = gimage + (((size_t)((b << 8) + c0)) << 10) + lin;
    #pragma unroll
    for (int c = 0; c < 32; c++) X[r * LS + c0 + c] = src[(size_t)c << 10];
  }
  __syncthreads();
  #pragma unroll 1
  for (int rb = 0; rb < 2; rb++) {
    gn_silu32(X, A, gn1w + (rb << 8), gn1b + (rb << 8), t);
    __syncthreads();
    gemm_f32<0, true>(A, c1w + rb * 589824, c1b + (rb << 8), H, nullptr);
    __syncthreads();
    gn_silu32(H, A, gn2w + (rb << 8), gn2b + (rb << 8), t);
    __syncthreads();
    gemm_f32<1, true>(A, c2w + rb * 589824, c2b + (rb << 8), nullptr, X);
    __syncthreads();
  }
  if (t < 64) {
    int r = t >> 1, j = t & 1;
    float s = clsb[j];
    const float* w = clsw + (j << 8);
    const float* x = X + r * LS;
    #pragma unroll 1
    for (int k = 0; k < 256; k += 4) {
      f32x4 wv = *(const f32x4*)(w + k);
      f32x4 xv = *(const f32x4*)(x + k);
      s += xv[0] * wv[0] + xv[1] * wv[1] + xv[2] * wv[2] + xv[3] * wv[3];
    }
    out[((size_t)(row0 + r) << 1) + j] = s;
  }
  gemm_f32<2, false>(X, w1, b1, H, nullptr);
  __syncthreads();
  gemm_f32<2, false>(H, w2, b2, A, nullptr);
  __syncthreads();
  if (t < 128) {
    int r = t >> 2, j = t & 3;
    float s = b3[j];
    const float* w = w3 + (j << 8);
    const float* x = A + r * LS;
    #pragma unroll 1
    for (int k = 0; k < 256; k += 4) {
      f32x4 wv = *(const f32x4*)(w + k);
      f32x4 xv = *(const f32x4*)(x + k);
      s += xv[0] * wv[0] + xv[1] * wv[1] + xv[2] * wv[2] + xv[3] * wv[3];
    }
    out[131072 + ((size_t)(row0 + r) << 2) + j] = sigm(s);
  }
}

extern "C" void kernel_launch(void* const* d_in, const int* in_sizes, int n_in,
                              void* d_out, int out_size, void* d_ws, size_t ws_size,
                              hipStream_t stream) {
  const float* gimage = (const float*)d_in[0];
  const int* pts = (const int*)d_in[1];
  const float* gn1w = (const float*)d_in[2];
  const float* gn1b = (const float*)d_in[3];
  const float* c1w = (const float*)d_in[4];
  const float* c1b = (const float*)d_in[5];
  const float* gn2w = (const float*)d_in[6];
  const float* gn2b = (const float*)d_in[7];
  const float* c2w = (const float*)d_in[8];
  const float* c2b = (const float*)d_in[9];
  const float* clsw = (const float*)d_in[10];
  const float* clsb = (const float*)d_in[11];
  const float* w1 = (const float*)d_in[12];
  const float* b1 = (const float*)d_in[13];
  const float* w2 = (const float*)d_in[14];
  const float* b2 = (const float*)d_in[15];
  const float* w3 = (const float*)d_in[16];
  const float* b3 = (const float*)d_in[17];

  if (ws_size >= (size_t)WS_NEED) {
    _Float16* ws = (_Float16*)d_ws;
    prep<<<512, 256, 0, stream>>>(c1w, c2w, w1, w2, ws);
    fused_mfma<<<2048, 256, 0, stream>>>(gimage, pts, gn1w, gn1b, c1b,
                                         gn2w, gn2b, c2b, clsw, clsb,
                                         b1, b2, w3, b3, ws, (float*)d_out);
  } else {
    fused_all<<<2048, 256, 0, stream>>>(gimage, pts, gn1w, gn1b, c1w, c1b,
                                        gn2w, gn2b, c2w, c2b, clsw, clsb,
                                        w1, b1, w2, b2, w3, b3, (float*)d_out);
  }
}

// Round 15
// 451.920 us; speedup vs baseline: 1.1859x; 1.1106x over previous
//
#include <hip/hip_runtime.h>

// Round 29: dual-tile interleave (64 rows/block, 2 independent chains/wave).
// R28: setprio null-to-negative (473 vs 447) -> reverted. R23 measured the
// GEMM chain 84%-stalled INTERNALLY (diag0 MfmaUtil 15.9%): single
// dependent chain per wave. This round: each wave owns TWO row-tiles ->
// (1) tile-B MFMAs/loads fill tile-A stalls (true independent ILP),
// (2) B operands shared (48 MFMAs cover each refill; weight traffic/row
// halves), (3) barriers per work halve. Unlike R17 (more waves, serial
// per-wave chains), the work lives inside the wave. Regs ~192 < 256 at
// bounds(256,2), all static indexing; LDS 71.7KB -> 2 blk/CU (R27 proved
// 2-block runs 477 even without this gain). Per-tile accumulation order
// unchanged -> bit-identical (absmax 0.0078125). Tripwires: WRITE ~1.5MB,
// dur must beat 447 else revert to R24. fp32 fallback retained.

typedef __attribute__((ext_vector_type(8))) _Float16 half8;
typedef __attribute__((ext_vector_type(4))) float f32x4;

#define AS 264   // fp16 A stride (+8 pad)

#define NHALF  393216    // elements per precision plane in ws
#define OFF_WC1 0        // [2][256][256]
#define OFF_WC2 131072
#define OFF_W1  262144   // [256][256]
#define OFF_W2  327680
#define WS_NEED 1572864  // bytes = 2 planes x 393216 halves x 2B

__device__ __forceinline__ float sigm(float y) { return 1.f / (1.f + __expf(-y)); }

// ---- DPP lane-sum helpers (R24 proven) ----
template <int CTRL>
__device__ __forceinline__ float dppadd(float v) {
  union { float f; int i; } u, r;
  u.f = v;
  r.i = __builtin_amdgcn_update_dpp(0, u.i, CTRL, 0xf, 0xf, true);
  return v + r.f;
}
#define DPP_X1 0xB1   // quad_perm [1,0,3,2]  == lane^1
#define DPP_X2 0x4E   // quad_perm [2,3,0,1]  == lane^2
#define DPP_X7 0x141  // row_half_mirror      == lane^7
#define DPP_XF 0x140  // row_mirror           == lane^15

__device__ __forceinline__ float gsum8(float v) {
  v = dppadd<DPP_X1>(v);
  v = dppadd<DPP_X2>(v);
  v = dppadd<DPP_X7>(v);
  return v;
}
__device__ __forceinline__ float gsum16(float v) {
  v = dppadd<DPP_X1>(v);
  v = dppadd<DPP_X2>(v);
  v = dppadd<DPP_X7>(v);
  v = dppadd<DPP_XF>(v);
  return v;
}

// ---- prep: pack weights as fp16 hi/lo planes: wsl = wsh + NHALF ----
__global__ __launch_bounds__(256) void prep(const float* __restrict__ c1w,
                                            const float* __restrict__ c2w,
                                            const float* __restrict__ w1,
                                            const float* __restrict__ w2,
                                            _Float16* __restrict__ ws) {
  int i = blockIdx.x * 256 + threadIdx.x;  // 0..131071
  {
    float v = c1w[(size_t)i * 9 + 4];
    _Float16 h = (_Float16)v;
    ws[OFF_WC1 + i] = h;
    ws[NHALF + OFF_WC1 + i] = (_Float16)(v - (float)h);
  }
  {
    float v = c2w[(size_t)i * 9 + 4];
    _Float16 h = (_Float16)v;
    ws[OFF_WC2 + i] = h;
    ws[NHALF + OFF_WC2 + i] = (_Float16)(v - (float)h);
  }
  if (i < 65536) {
    float v = w1[i];
    _Float16 h = (_Float16)v;
    ws[OFF_W1 + i] = h;
    ws[NHALF + OFF_W1 + i] = (_Float16)(v - (float)h);
    v = w2[i];
    h = (_Float16)v;
    ws[OFF_W2 + i] = h;
    ws[NHALF + OFF_W2 + i] = (_Float16)(v - (float)h);
  }
}

// ---- hi/lo split store into A planes ----
__device__ __forceinline__ void hl_store(_Float16* __restrict__ Ah,
                                         _Float16* __restrict__ Al,
                                         int idx, float v) {
  _Float16 h = (_Float16)v;
  Ah[idx] = h;
  Al[idx] = (_Float16)(v - (float)h);
}

// ---- B fragment registers (kt batch), preloaded EARLY so loads complete
// during the preceding epilogue's VALU work. SHARED by both tiles. ----
struct BF { half8 h[4], l[4]; };

__device__ __forceinline__ void preloadB(BF& B,
    const _Float16* __restrict__ Wh, const _Float16* __restrict__ Wl,
    size_t boff) {
  #pragma unroll
  for (int nt = 0; nt < 4; nt++) {
    B.h[nt] = *(const half8*)(Wh + boff + (nt << 12));
    B.l[nt] = *(const half8*)(Wl + boff + (nt << 12));
  }
}

// ---- dual-tile 32x256 @ 256x256 split-fp16 MFMA: two independent acc
// chains interleaved, sharing the B registers. Per-tile, per-element
// accumulation order (ah*bh, ah*bl, al*bh; kt ascending) is identical to
// R24 -> bit-identical. 48 MFMAs cover each per-kt B refill. Entry
// barrier makes A-plane writes visible; callers must NOT sync before. ----
__device__ __forceinline__ void mfma_dual(f32x4 accA[2][4], f32x4 accB[2][4],
    BF& B,
    const _Float16* __restrict__ AhA, const _Float16* __restrict__ AlA,
    const _Float16* __restrict__ AhB, const _Float16* __restrict__ AlB,
    const _Float16* __restrict__ Wh, const _Float16* __restrict__ Wl,
    int aoff, size_t boff) {
  #pragma unroll
  for (int mt = 0; mt < 2; mt++)
    #pragma unroll
    for (int nt = 0; nt < 4; nt++) {
      accA[mt][nt] = (f32x4){0.f, 0.f, 0.f, 0.f};
      accB[mt][nt] = (f32x4){0.f, 0.f, 0.f, 0.f};
    }
  __syncthreads();
  #pragma unroll
  for (int kt = 0; kt < 8; kt++) {
    half8 a0hA = *(const half8*)(AhA + aoff + kt * 32);
    half8 a1hA = *(const half8*)(AhA + aoff + 16 * AS + kt * 32);
    half8 a0lA = *(const half8*)(AlA + aoff + kt * 32);
    half8 a1lA = *(const half8*)(AlA + aoff + 16 * AS + kt * 32);
    half8 a0hB = *(const half8*)(AhB + aoff + kt * 32);
    half8 a1hB = *(const half8*)(AhB + aoff + 16 * AS + kt * 32);
    half8 a0lB = *(const half8*)(AlB + aoff + kt * 32);
    half8 a1lB = *(const half8*)(AlB + aoff + 16 * AS + kt * 32);
    #pragma unroll
    for (int nt = 0; nt < 4; nt++)
      accA[0][nt] = __builtin_amdgcn_mfma_f32_16x16x32_f16(a0hA, B.h[nt], accA[0][nt], 0, 0, 0);
    #pragma unroll
    for (int nt = 0; nt < 4; nt++)
      accB[0][nt] = __builtin_amdgcn_mfma_f32_16x16x32_f16(a0hB, B.h[nt], accB[0][nt], 0, 0, 0);
    #pragma unroll
    for (int nt = 0; nt < 4; nt++)
      accA[1][nt] = __builtin_amdgcn_mfma_f32_16x16x32_f16(a1hA, B.h[nt], accA[1][nt], 0, 0, 0);
    #pragma unroll
    for (int nt = 0; nt < 4; nt++)
      accB[1][nt] = __builtin_amdgcn_mfma_f32_16x16x32_f16(a1hB, B.h[nt], accB[1][nt], 0, 0, 0);
    #pragma unroll
    for (int nt = 0; nt < 4; nt++)
      accA[0][nt] = __builtin_amdgcn_mfma_f32_16x16x32_f16(a0hA, B.l[nt], accA[0][nt], 0, 0, 0);
    #pragma unroll
    for (int nt = 0; nt < 4; nt++)
      accB[0][nt] = __builtin_amdgcn_mfma_f32_16x16x32_f16(a0hB, B.l[nt], accB[0][nt], 0, 0, 0);
    #pragma unroll
    for (int nt = 0; nt < 4; nt++)
      accA[1][nt] = __builtin_amdgcn_mfma_f32_16x16x32_f16(a1hA, B.l[nt], accA[1][nt], 0, 0, 0);
    #pragma unroll
    for (int nt = 0; nt < 4; nt++)
      accB[1][nt] = __builtin_amdgcn_mfma_f32_16x16x32_f16(a1hB, B.l[nt], accB[1][nt], 0, 0, 0);
    #pragma unroll
    for (int nt = 0; nt < 4; nt++)
      accA[0][nt] = __builtin_amdgcn_mfma_f32_16x16x32_f16(a0lA, B.h[nt], accA[0][nt], 0, 0, 0);
    #pragma unroll
    for (int nt = 0; nt < 4; nt++)
      accB[0][nt] = __builtin_amdgcn_mfma_f32_16x16x32_f16(a0lB, B.h[nt], accB[0][nt], 0, 0, 0);
    #pragma unroll
    for (int nt = 0; nt < 4; nt++)
      accA[1][nt] = __builtin_amdgcn_mfma_f32_16x16x32_f16(a1lA, B.h[nt], accA[1][nt], 0, 0, 0);
    #pragma unroll
    for (int nt = 0; nt < 4; nt++)
      accB[1][nt] = __builtin_amdgcn_mfma_f32_16x16x32_f16(a1lB, B.h[nt], accB[1][nt], 0, 0, 0);
    if (kt < 7) {
      #pragma unroll
      for (int nt = 0; nt < 4; nt++) {
        B.h[nt] = *(const half8*)(Wh + boff + (nt << 12) + (kt + 1) * 32);
        B.l[nt] = *(const half8*)(Wl + boff + (nt << 12) + (kt + 1) * 32);
      }
    }
  }
}

// ---- GN(32 groups x 8 chans)+SiLU from residual regs (C-layout) -> A ----
__device__ __forceinline__ void gn_x_to_A(const float x[2][4][4],
    const float* __restrict__ gnw, const float* __restrict__ gnb,
    int col, int quad, int nb,
    _Float16* __restrict__ Ah, _Float16* __restrict__ Al) {
  #pragma unroll
  for (int nt = 0; nt < 4; nt++) {
    int n = nb + (nt << 4) + col;
    float gwv = gnw[n], gbv = gnb[n];
    #pragma unroll
    for (int mt = 0; mt < 2; mt++) {
      #pragma unroll
      for (int rg = 0; rg < 4; rg++) {
        float v = x[mt][nt][rg];
        float s = gsum8(v);
        float q = gsum8(v * v);
        float mu = s * 0.125f;
        float rs = rsqrtf(q * 0.125f - mu * mu + 1e-5f);
        float y = (v - mu) * rs * gwv + gbv;
        float sv = y * sigm(y);
        hl_store(Ah, Al, ((mt << 4) + (quad << 2) + rg) * AS + n, sv);
      }
    }
  }
}

// ---- (acc + bias) -> GN+SiLU -> A, all in registers ----
__device__ __forceinline__ void epi_gn_to_A(const f32x4 acc[2][4],
    const float* __restrict__ bias,
    const float* __restrict__ gnw, const float* __restrict__ gnb,
    int col, int quad, int nb,
    _Float16* __restrict__ Ah, _Float16* __restrict__ Al) {
  #pragma unroll
  for (int nt = 0; nt < 4; nt++) {
    int n = nb + (nt << 4) + col;
    float bv = bias[n];
    float gwv = gnw[n], gbv = gnb[n];
    #pragma unroll
    for (int mt = 0; mt < 2; mt++) {
      #pragma unroll
      for (int rg = 0; rg < 4; rg++) {
        float v = acc[mt][nt][rg] + bv;
        float s = gsum8(v);
        float q = gsum8(v * v);
        float mu = s * 0.125f;
        float rs = rsqrtf(q * 0.125f - mu * mu + 1e-5f);
        float y = (v - mu) * rs * gwv + gbv;
        float sv = y * sigm(y);
        hl_store(Ah, Al, ((mt << 4) + (quad << 2) + rg) * AS + n, sv);
      }
    }
  }
}

// ---- relu(acc + bias) -> A ----
__device__ __forceinline__ void epi_relu_to_A(const f32x4 acc[2][4],
    const float* __restrict__ bias, int col, int quad, int nb,
    _Float16* __restrict__ Ah, _Float16* __restrict__ Al) {
  #pragma unroll
  for (int nt = 0; nt < 4; nt++) {
    int n = nb + (nt << 4) + col;
    float bv = bias[n];
    #pragma unroll
    for (int mt = 0; mt < 2; mt++)
      #pragma unroll
      for (int rg = 0; rg < 4; rg++)
        hl_store(Ah, Al, ((mt << 4) + (quad << 2) + rg) * AS + n,
                 fmaxf(acc[mt][nt][rg] + bv, 0.f));
  }
}

// ---- gather one 32-row tile into C-layout registers ----
__device__ __forceinline__ void gatherX(float x[2][4][4],
    const float* __restrict__ gimage, const int* __restrict__ pts,
    int tbase, int rbase, int nb, int col) {
  int lin[2][4];
  #pragma unroll
  for (int mt = 0; mt < 2; mt++)
    #pragma unroll
    for (int rg = 0; rg < 4; rg++) {
      int grow = tbase + (mt << 4) + rbase + rg;
      int p0 = pts[2 * grow], p1 = pts[2 * grow + 1];
      lin[mt][rg] = ((p0 >> 3) << 5) + (p1 >> 3);
    }
  const float* gbase = gimage + (((size_t)((tbase >> 11) << 8)) << 10);
  #pragma unroll
  for (int nt = 0; nt < 4; nt++) {
    const float* gc = gbase + (((size_t)(nb + (nt << 4) + col)) << 10);
    #pragma unroll
    for (int mt = 0; mt < 2; mt++)
      #pragma unroll
      for (int rg = 0; rg < 4; rg++)
        x[mt][nt][rg] = gc[lin[mt][rg]];
  }
}

__global__ __launch_bounds__(256, 2) void fused_mfma(
    const float* __restrict__ gimage, const int* __restrict__ pts,
    const float* __restrict__ gn1w, const float* __restrict__ gn1b,
    const float* __restrict__ c1b,
    const float* __restrict__ gn2w, const float* __restrict__ gn2b,
    const float* __restrict__ c2b,
    const float* __restrict__ clsw, const float* __restrict__ clsb,
    const float* __restrict__ b1, const float* __restrict__ b2,
    const float* __restrict__ w3, const float* __restrict__ b3,
    const _Float16* __restrict__ ws, float* __restrict__ out) {
  __shared__ _Float16 AhA[32 * AS], AlA[32 * AS];   // tile A activation
  __shared__ _Float16 AhB[32 * AS], AlB[32 * AS];   // tile B activation
  __shared__ float red[4][64][4];                   // head reduction scratch

  const int t = threadIdx.x;
  const int w = t >> 6;
  const int lane = t & 63;
  const int col = lane & 15;
  const int quad = lane >> 4;
  const int nb = w << 6;              // wave's 64-col slab
  // XCD-chunked bijective swizzle (1024 % 8 == 0; chunk = 128)
  const int bsw = ((blockIdx.x & 7) << 7) | (blockIdx.x >> 3);
  const int row0 = bsw << 6;          // 64 rows per block (one batch-aligned)
  const int rbase = quad << 2;

  const int aoff = col * AS + (quad << 3);
  const size_t boff = (((size_t)(nb + col)) << 8) + (quad << 3);
  const _Float16* wsl = ws + NHALF;

  // ---- gather both tiles ----
  float xA[2][4][4], xB[2][4][4];
  gatherX(xA, gimage, pts, row0, rbase, nb, col);
  gatherX(xB, gimage, pts, row0 + 32, rbase, nb, col);

  f32x4 accA[2][4], accB[2][4];
  BF B;

  // ---- 2x ResBlock; B issued one epilogue ahead, shared by both tiles ----
  preloadB(B, ws + OFF_WC1, wsl + OFF_WC1, boff);
  #pragma unroll 1
  for (int rb = 0; rb < 2; rb++) {
    gn_x_to_A(xA, gn1w + (rb << 8), gn1b + (rb << 8), col, quad, nb, AhA, AlA);
    gn_x_to_A(xB, gn1w + (rb << 8), gn1b + (rb << 8), col, quad, nb, AhB, AlB);
    mfma_dual(accA, accB, B, AhA, AlA, AhB, AlB,
              ws + OFF_WC1 + (rb << 16), wsl + OFF_WC1 + (rb << 16),
              aoff, boff);
    __syncthreads();
    preloadB(B, ws + OFF_WC2 + (rb << 16), wsl + OFF_WC2 + (rb << 16), boff);
    epi_gn_to_A(accA, c1b + (rb << 8), gn2w + (rb << 8), gn2b + (rb << 8),
                col, quad, nb, AhA, AlA);
    epi_gn_to_A(accB, c1b + (rb << 8), gn2w + (rb << 8), gn2b + (rb << 8),
                col, quad, nb, AhB, AlB);
    mfma_dual(accA, accB, B, AhA, AlA, AhB, AlB,
              ws + OFF_WC2 + (rb << 16), wsl + OFF_WC2 + (rb << 16),
              aoff, boff);
    __syncthreads();
    if (rb == 0)
      preloadB(B, ws + OFF_WC1 + 65536, wsl + OFF_WC1 + 65536, boff);
    else
      preloadB(B, ws + OFF_W1, wsl + OFF_W1, boff);
    #pragma unroll
    for (int nt = 0; nt < 4; nt++) {
      float bv = c2b[(rb << 8) + nb + (nt << 4) + col];
      #pragma unroll
      for (int mt = 0; mt < 2; mt++)
        #pragma unroll
        for (int rg = 0; rg < 4; rg++) {
          xA[mt][nt][rg] += accA[mt][nt][rg] + bv;
          xB[mt][nt][rg] += accB[mt][nt][rg] + bv;
        }
    }
  }

  // ---- A = hl(x) for the MLP (both tiles); cls partials from x (regs) ----
  #pragma unroll
  for (int nt = 0; nt < 4; nt++) {
    int n = nb + (nt << 4) + col;
    #pragma unroll
    for (int mt = 0; mt < 2; mt++)
      #pragma unroll
      for (int rg = 0; rg < 4; rg++) {
        hl_store(AhA, AlA, ((mt << 4) + rbase + rg) * AS + n, xA[mt][nt][rg]);
        hl_store(AhB, AlB, ((mt << 4) + rbase + rg) * AS + n, xB[mt][nt][rg]);
      }
  }
  {
    float pc[2][2][4];
    // tile A
    #pragma unroll
    for (int j = 0; j < 2; j++) {
      #pragma unroll
      for (int mt = 0; mt < 2; mt++)
        #pragma unroll
        for (int rg = 0; rg < 4; rg++)
          pc[j][mt][rg] = 0.f;
      #pragma unroll
      for (int nt = 0; nt < 4; nt++) {
        float wv = clsw[(j << 8) + nb + (nt << 4) + col];
        #pragma unroll
        for (int mt = 0; mt < 2; mt++)
          #pragma unroll
          for (int rg = 0; rg < 4; rg++)
            pc[j][mt][rg] += xA[mt][nt][rg] * wv;
      }
    }
    #pragma unroll
    for (int j = 0; j < 2; j++)
      #pragma unroll
      for (int mt = 0; mt < 2; mt++)
        #pragma unroll
        for (int rg = 0; rg < 4; rg++) {
          float p = gsum16(pc[j][mt][rg]);
          if (col == 0) red[w][(mt << 4) + rbase + rg][j] = p;
        }
    // tile B
    #pragma unroll
    for (int j = 0; j < 2; j++) {
      #pragma unroll
      for (int mt = 0; mt < 2; mt++)
        #pragma unroll
        for (int rg = 0; rg < 4; rg++)
          pc[j][mt][rg] = 0.f;
      #pragma unroll
      for (int nt = 0; nt < 4; nt++) {
        float wv = clsw[(j << 8) + nb + (nt << 4) + col];
        #pragma unroll
        for (int mt = 0; mt < 2; mt++)
          #pragma unroll
          for (int rg = 0; rg < 4; rg++)
            pc[j][mt][rg] += xB[mt][nt][rg] * wv;
      }
    }
    #pragma unroll
    for (int j = 0; j < 2; j++)
      #pragma unroll
      for (int mt = 0; mt < 2; mt++)
        #pragma unroll
        for (int rg = 0; rg < 4; rg++) {
          float p = gsum16(pc[j][mt][rg]);
          if (col == 0) red[w][32 + (mt << 4) + rbase + rg][j] = p;
        }
  }

  // ---- MLP gemm1 (w1); cls finalize rides alongside (red synced by the
  // mfma_dual entry barrier) ----
  mfma_dual(accA, accB, B, AhA, AlA, AhB, AlB,
            ws + OFF_W1, wsl + OFF_W1, aoff, boff);
  if (t < 128) {
    int r = t >> 1, j = t & 1;
    out[((size_t)(row0 + r) << 1) + j] =
        clsb[j] + red[0][r][j] + red[1][r][j] + red[2][r][j] + red[3][r][j];
  }
  __syncthreads();
  preloadB(B, ws + OFF_W2, wsl + OFF_W2, boff);
  epi_relu_to_A(accA, b1, col, quad, nb, AhA, AlA);
  epi_relu_to_A(accB, b1, col, quad, nb, AhB, AlB);

  // ---- MLP gemm2 (w2) -> relu -> w3 partials in regs (both tiles) ----
  mfma_dual(accA, accB, B, AhA, AlA, AhB, AlB,
            ws + OFF_W2, wsl + OFF_W2, aoff, boff);
  __syncthreads();
  {
    float pb[4][2][4];
    // tile A
    #pragma unroll
    for (int j = 0; j < 4; j++)
      #pragma unroll
      for (int mt = 0; mt < 2; mt++)
        #pragma unroll
        for (int rg = 0; rg < 4; rg++)
          pb[j][mt][rg] = 0.f;
    #pragma unroll
    for (int nt = 0; nt < 4; nt++) {
      int n = nb + (nt << 4) + col;
      float bv = b2[n];
      float w0 = w3[n], w1v = w3[256 + n], w2v = w3[512 + n], w3v = w3[768 + n];
      #pragma unroll
      for (int mt = 0; mt < 2; mt++)
        #pragma unroll
        for (int rg = 0; rg < 4; rg++) {
          float v = fmaxf(accA[mt][nt][rg] + bv, 0.f);
          pb[0][mt][rg] += v * w0;
          pb[1][mt][rg] += v * w1v;
          pb[2][mt][rg] += v * w2v;
          pb[3][mt][rg] += v * w3v;
        }
    }
    #pragma unroll
    for (int j = 0; j < 4; j++)
      #pragma unroll
      for (int mt = 0; mt < 2; mt++)
        #pragma unroll
        for (int rg = 0; rg < 4; rg++) {
          float p = gsum16(pb[j][mt][rg]);
          if (col == 0) red[w][(mt << 4) + rbase + rg][j] = p;
        }
    // tile B
    #pragma unroll
    for (int j = 0; j < 4; j++)
      #pragma unroll
      for (int mt = 0; mt < 2; mt++)
        #pragma unroll
        for (int rg = 0; rg < 4; rg++)
          pb[j][mt][rg] = 0.f;
    #pragma unroll
    for (int nt = 0; nt < 4; nt++) {
      int n = nb + (nt << 4) + col;
      float bv = b2[n];
      float w0 = w3[n], w1v = w3[256 + n], w2v = w3[512 + n], w3v = w3[768 + n];
      #pragma unroll
      for (int mt = 0; mt < 2; mt++)
        #pragma unroll
        for (int rg = 0; rg < 4; rg++) {
          float v = fmaxf(accB[mt][nt][rg] + bv, 0.f);
          pb[0][mt][rg] += v * w0;
          pb[1][mt][rg] += v * w1v;
          pb[2][mt][rg] += v * w2v;
          pb[3][mt][rg] += v * w3v;
        }
    }
    #pragma unroll
    for (int j = 0; j < 4; j++)
      #pragma unroll
      for (int mt = 0; mt < 2; mt++)
        #pragma unroll
        for (int rg = 0; rg < 4; rg++) {
          float p = gsum16(pb[j][mt][rg]);
          if (col == 0) red[w][32 + (mt << 4) + rbase + rg][j] = p;
        }
  }
  __syncthreads();
  {
    int r = t >> 2, j = t & 3;   // 256 threads = 64 rows x 4
    float s = b3[j] + red[0][r][j] + red[1][r][j] + red[2][r][j] + red[3][r][j];
    out[131072 + ((size_t)(row0 + r) << 2) + j] = sigm(s);
  }
}

// ================= fp32 fallback (R11, proven) for tiny ws =================
#define LS 260
template <int EPI, bool CONV>
__device__ __forceinline__ void gemm_f32(const float* __restrict__ src,
                                         const float* __restrict__ W,
                                         const float* __restrict__ bias,
                                         float* __restrict__ dst,
                                         float* __restrict__ X) {
  const int n = threadIdx.x;
  float acc[32];
  #pragma unroll
  for (int r = 0; r < 32; r++) acc[r] = 0.f;
  #pragma unroll 1
  for (int k = 0; k < 256; k += 8) {
    float w[8];
    if (CONV) {
      #pragma unroll
      for (int j = 0; j < 8; j++) w[j] = W[(size_t)((n << 8) + k + j) * 9 + 4];
    } else {
      f32x4 wa = *(const f32x4*)(W + (n << 8) + k);
      f32x4 wb = *(const f32x4*)(W + (n << 8) + k + 4);
      w[0] = wa[0]; w[1] = wa[1]; w[2] = wa[2]; w[3] = wa[3];
      w[4] = wb[0]; w[5] = wb[1]; w[6] = wb[2]; w[7] = wb[3];
    }
    #pragma unroll
    for (int r = 0; r < 32; r++) {
      const float* xr = src + r * LS + k;
      f32x4 a0 = *(const f32x4*)xr, a1 = *(const f32x4*)(xr + 4);
      acc[r] += a0[0] * w[0] + a0[1] * w[1] + a0[2] * w[2] + a0[3] * w[3]
              + a1[0] * w[4] + a1[1] * w[5] + a1[2] * w[6] + a1[3] * w[7];
    }
  }
  float bv = bias[n];
  #pragma unroll
  for (int r = 0; r < 32; r++) {
    float v = acc[r] + bv;
    if (EPI == 0) dst[r * LS + n] = v;
    else if (EPI == 1) X[r * LS + n] += v;
    else dst[r * LS + n] = fmaxf(v, 0.f);
  }
}
__device__ __forceinline__ void gn_silu32(const float* __restrict__ src,
                                          float* __restrict__ dst,
                                          const float* __restrict__ gw,
                                          const float* __restrict__ gb, int t) {
  #pragma unroll
  for (int i = 0; i < 4; i++) {
    int task = (i << 8) + t;
    int r = task >> 5, g = task & 31;
    const float* x = src + r * LS + (g << 3);
    f32x4 x0 = *(const f32x4*)x, x1 = *(const f32x4*)(x + 4);
    float xx[8] = {x0[0], x0[1], x0[2], x0[3], x1[0], x1[1], x1[2], x1[3]};
    float s = 0.f, q = 0.f;
    #pragma unroll
    for (int j = 0; j < 8; j++) { s += xx[j]; q += xx[j] * xx[j]; }
    float mu = s * 0.125f;
    float rs = rsqrtf(q * 0.125f - mu * mu + 1e-5f);
    const float* w = gw + (g << 3);
    const float* b = gb + (g << 3);
    float* d = dst + r * LS + (g << 3);
    #pragma unroll
    for (int j = 0; j < 8; j++) {
      float y = (xx[j] - mu) * rs * w[j] + b[j];
      d[j] = y * sigm(y);
    }
  }
}
__global__ __launch_bounds__(256, 1) void fused_all(
    const float* __restrict__ gimage, const int* __restrict__ pts,
    const float* __restrict__ gn1w, const float* __restrict__ gn1b,
    const float* __restrict__ c1w, const float* __restrict__ c1b,
    const float* __restrict__ gn2w, const float* __restrict__ gn2b,
    const float* __restrict__ c2w, const float* __restrict__ c2b,
    const float* __restrict__ clsw, const float* __restrict__ clsb,
    const float* __restrict__ w1, const float* __restrict__ b1,
    const float* __restrict__ w2, const float* __restrict__ b2,
    const float* __restrict__ w3, const float* __restrict__ b3,
    float* __restrict__ out) {
  __shared__ float X[32 * LS];
  __shared__ float A[32 * LS];
  __shared__ float H[32 * LS];
  const int t = threadIdx.x;
  const int row0 = blockIdx.x << 5;
  {
    int r = t >> 3;
    int c0 = (t & 7) << 5;
    int grow = row0 + r;
    int p0 = pts[2 * grow], p1 = pts[2 * grow + 1];
    int lin = ((p0 >> 3) << 5) + (p1 >> 3);
    int b = grow >> 11;
    const float* src = gimage + (((size_t)((b << 8) + c0)) << 10) + lin;
    #pragma unroll
    for (int c = 0; c < 32; c++) X[r * LS + c0 + c] = src[(size_t)c << 10];
  }
  __syncthreads();
  #pragma unroll 1
  for (int rb = 0; rb < 2; rb++) {
    gn_silu32(X, A, gn1w + (rb << 8), gn1b + (rb << 8), t);
    __syncthreads();
    gemm_f32<0, true>(A, c1w + rb * 589824, c1b + (rb << 8), H, nullptr);
    __syncthreads();
    gn_silu32(H, A, gn2w + (rb << 8), gn2b + (rb << 8), t);
    __syncthreads();
    gemm_f32<1, true>(A, c2w + rb * 589824, c2b + (rb << 8), nullptr, X);
    __syncthreads();
  }
  if (t < 64) {
    int r = t >> 1, j = t & 1;
    float s = clsb[j];
    const float* w = clsw + (j << 8);
    const float* x = X + r * LS;
    #pragma unroll 1
    for (int k = 0; k < 256; k += 4) {
      f32x4 wv = *(const f32x4*)(w + k);
      f32x4 xv = *(const f32x4*)(x + k);
      s += xv[0] * wv[0] + xv[1] * wv[1] + xv[2] * wv[2] + xv[3] * wv[3];
    }
    out[((size_t)(row0 + r) << 1) + j] = s;
  }
  gemm_f32<2, false>(X, w1, b1, H, nullptr);
  __syncthreads();
  gemm_f32<2, false>(H, w2, b2, A, nullptr);
  __syncthreads();
  if (t < 128) {
    int r = t >> 2, j = t & 3;
    float s = b3[j];
    const float* w = w3 + (j << 8);
    const float* x = A + r * LS;
    #pragma unroll 1
    for (int k = 0; k < 256; k += 4) {
      f32x4 wv = *(const f32x4*)(w + k);
      f32x4 xv = *(const f32x4*)(x + k);
      s += xv[0] * wv[0] + xv[1] * wv[1] + xv[2] * wv[2] + xv[3] * wv[3];
    }
    out[131072 + ((size_t)(row0 + r) << 2) + j] = sigm(s);
  }
}

extern "C" void kernel_launch(void* const* d_in, const int* in_sizes, int n_in,
                              void* d_out, int out_size, void* d_ws, size_t ws_size,
                              hipStream_t stream) {
  const float* gimage = (const float*)d_in[0];
  const int* pts = (const int*)d_in[1];
  const float* gn1w = (const float*)d_in[2];
  const float* gn1b = (const float*)d_in[3];
  const float* c1w = (const float*)d_in[4];
  const float* c1b = (const float*)d_in[5];
  const float* gn2w = (const float*)d_in[6];
  const float* gn2b = (const float*)d_in[7];
  const float* c2w = (const float*)d_in[8];
  const float* c2b = (const float*)d_in[9];
  const float* clsw = (const float*)d_in[10];
  const float* clsb = (const float*)d_in[11];
  const float* w1 = (const float*)d_in[12];
  const float* b1 = (const float*)d_in[13];
  const float* w2 = (const float*)d_in[14];
  const float* b2 = (const float*)d_in[15];
  const float* w3 = (const float*)d_in[16];
  const float* b3 = (const float*)d_in[17];

  if (ws_size >= (size_t)WS_NEED) {
    _Float16* ws = (_Float16*)d_ws;
    prep<<<512, 256, 0, stream>>>(c1w, c2w, w1, w2, ws);
    fused_mfma<<<1024, 256, 0, stream>>>(gimage, pts, gn1w, gn1b, c1b,
                                         gn2w, gn2b, c2b, clsw, clsb,
                                         b1, b2, w3, b3, ws, (float*)d_out);
  } else {
    fused_all<<<2048, 256, 0, stream>>>(gimage, pts, gn1w, gn1b, c1w, c1b,
                                        gn2w, gn2b, c2w, c2b, clsw, clsb,
                                        w1, b1, w2, b2, w3, b3, (float*)d_out);
  }
}